// Round 6
// baseline (339.260 us; speedup 1.0000x reference)
//
#include <hip/hip_runtime.h>
#include <hip/hip_fp16.h>

#define M_TOK 16384
#define H_DIM 1024
#define F_DIM 4096

typedef __attribute__((ext_vector_type(4))) int int4v;

// ---------------- workspace layout (bytes) ----------------
static const size_t OFF_H2    = 0;                       // fp16 [M,F]  134,217,728
static const size_t OFF_Q2    = OFF_H2   + 134217728ULL; // int8 [M,F]   67,108,864
static const size_t OFF_XQ    = OFF_Q2   + 67108864ULL;  // int8 [M,H]   16,777,216
static const size_t OFF_WQU   = OFF_XQ   + 16777216ULL;  // int8 [F,H]    4,194,304
static const size_t OFF_WQD   = OFF_WQU  + 4194304ULL;   // int8 [H,F]    4,194,304
static const size_t OFF_DQX   = OFF_WQD  + 4194304ULL;   // f32 [M]          65,536
static const size_t OFF_DQ2   = OFF_DQX  + 65536ULL;     // f32 [M]          65,536
static const size_t OFF_PMAX  = OFF_DQ2  + 65536ULL;     // f32 [64,M]    4,194,304
static const size_t OFF_WPART = OFF_PMAX + 4194304ULL;   // f32 [2048]        8,192
static const size_t OFF_WSC   = OFF_WPART+ 8192ULL;      // f32 [4]
static const size_t WS_NEEDED = OFF_WSC  + 16ULL;

__device__ __forceinline__ void ldg_lds16(const void* g, void* l) {
  __builtin_amdgcn_global_load_lds(
      (const __attribute__((address_space(1))) void*)g,
      (__attribute__((address_space(3))) void*)l, 16, 0, 0);
}

// ---------------- K1: |w| partial sums (deterministic) ----------------
__global__ __launch_bounds__(256) void k_wabs(const float* __restrict__ wu,
                                              const float* __restrict__ wd,
                                              float* __restrict__ part) {
  const int b = blockIdx.x;                 // 0..2047 (1024 per tensor)
  const float* w = (b < 1024) ? wu : wd;
  const int cb = b & 1023;
  const size_t base = (size_t)cb * 4096 + threadIdx.x * 4;
  float s = 0.0f;
#pragma unroll
  for (int it = 0; it < 4; ++it) {
    const float4 v = *(const float4*)(w + base + it * 1024);
    s += fabsf(v.x) + fabsf(v.y) + fabsf(v.z) + fabsf(v.w);
  }
#pragma unroll
  for (int sh = 32; sh; sh >>= 1) s += __shfl_xor(s, sh, 64);
  __shared__ float red[4];
  if ((threadIdx.x & 63) == 0) red[threadIdx.x >> 6] = s;
  __syncthreads();
  if (threadIdx.x == 0) part[b] = red[0] + red[1] + red[2] + red[3];
}

// ---------------- K2: finalize per-tensor scale ----------------
__global__ __launch_bounds__(256) void k_wscale(const float* __restrict__ part,
                                                float* __restrict__ wsc) {
  const int b = blockIdx.x;                 // 0: w_up, 1: w_down
  const float* p = part + b * 1024;
  float s = p[threadIdx.x] + p[threadIdx.x + 256] + p[threadIdx.x + 512] + p[threadIdx.x + 768];
#pragma unroll
  for (int sh = 32; sh; sh >>= 1) s += __shfl_xor(s, sh, 64);
  __shared__ float red[4];
  if ((threadIdx.x & 63) == 0) red[threadIdx.x >> 6] = s;
  __syncthreads();
  if (threadIdx.x == 0) {
    const float mean = (red[0] + red[1] + red[2] + red[3]) * (1.0f / 4194304.0f);
    const float c = fmaxf(mean, 1e-5f);
    wsc[b * 2]     = c;         // dequant factor (1/scale)
    wsc[b * 2 + 1] = 1.0f / c;  // scale
  }
}

// ---------------- K3: ternary-quantize both weights ----------------
__global__ __launch_bounds__(256) void k_wquant(const float* __restrict__ wu,
                                                const float* __restrict__ wd,
                                                char* __restrict__ qu,
                                                char* __restrict__ qd,
                                                const float* __restrict__ wsc) {
  const size_t t = (size_t)blockIdx.x * 256 + threadIdx.x;  // 0..2097151
  const float* w; char* q; float scale; size_t i;
  if (t < 1048576) { w = wu; q = qu; scale = wsc[1]; i = t * 4; }
  else             { w = wd; q = qd; scale = wsc[3]; i = (t - 1048576) * 4; }
  const float4 v = *(const float4*)(w + i);
  const int a = (int)rintf(fminf(fmaxf(v.x * scale, -1.0f), 1.0f));
  const int b = (int)rintf(fminf(fmaxf(v.y * scale, -1.0f), 1.0f));
  const int c = (int)rintf(fminf(fmaxf(v.z * scale, -1.0f), 1.0f));
  const int d = (int)rintf(fminf(fmaxf(v.w * scale, -1.0f), 1.0f));
  *(unsigned*)(q + i) = (a & 255) | ((b & 255) << 8) | ((c & 255) << 16) | ((d & 255) << 24);
}

// ---------------- K4: fused RMSNorm + act_quant ----------------
__global__ __launch_bounds__(256) void k_rmsnorm_quant(const float* __restrict__ x,
                                                       const float* __restrict__ nw,
                                                       char* __restrict__ xq,
                                                       float* __restrict__ dqx) {
  const int row = blockIdx.x;
  const int t = threadIdx.x;
  const float4 v = *(const float4*)(x + (size_t)row * H_DIM + t * 4);
  float ss = v.x * v.x + v.y * v.y + v.z * v.z + v.w * v.w;
#pragma unroll
  for (int sh = 32; sh; sh >>= 1) ss += __shfl_xor(ss, sh, 64);
  __shared__ float red[4];
  __shared__ float redm[4];
  if ((t & 63) == 0) red[t >> 6] = ss;
  __syncthreads();
  ss = red[0] + red[1] + red[2] + red[3];
  const float rinv = 1.0f / sqrtf(ss * (1.0f / 1024.0f) + 1e-6f);
  const float4 w4 = *(const float4*)(nw + t * 4);
  float4 n;
  n.x = v.x * rinv * w4.x;  n.y = v.y * rinv * w4.y;
  n.z = v.z * rinv * w4.z;  n.w = v.w * rinv * w4.w;
  float am = fmaxf(fmaxf(fabsf(n.x), fabsf(n.y)), fmaxf(fabsf(n.z), fabsf(n.w)));
#pragma unroll
  for (int sh = 32; sh; sh >>= 1) am = fmaxf(am, __shfl_xor(am, sh, 64));
  if ((t & 63) == 0) redm[t >> 6] = am;
  __syncthreads();
  am = fmaxf(fmaxf(redm[0], redm[1]), fmaxf(redm[2], redm[3]));
  am = fmaxf(am, 1e-5f);
  const float scale = 127.0f / am;
  const int qa = (int)rintf(fminf(fmaxf(n.x * scale, -128.0f), 127.0f));
  const int qb = (int)rintf(fminf(fmaxf(n.y * scale, -128.0f), 127.0f));
  const int qc = (int)rintf(fminf(fmaxf(n.z * scale, -128.0f), 127.0f));
  const int qd = (int)rintf(fminf(fmaxf(n.w * scale, -128.0f), 127.0f));
  *(unsigned*)(xq + (size_t)row * H_DIM + t * 4) =
      (qa & 255) | ((qb & 255) << 8) | ((qc & 255) << 16) | ((qd & 255) << 24);
  if (t == 0) dqx[row] = am * (1.0f / 127.0f);
}

// ---------------- shared int8 GEMM core: 256x256, BK=128, m201 8-barrier phases --------
// Layout (proven conflict-free, 0 SQ_LDS_BANK_CONFLICT measured r2/r5):
// buffer p at p*65536: A 256 rows x 128B at +0, B at +32768. Seg slot s of row r
// holds global k-seg s ^ (r&7); ds_read slot (ks*4+q)^(fr&7); staging DMA
// lane-linear (thread t -> slot t*16 within each 64-row 8KB quarter).
//
// Schedule = m201's verified phase skeleton (the r5 delta: per-phase DOUBLE
// barriers + lgkmcnt(0) + sched_barrier(0) before each MFMA cluster — m196's
// isolated lever; r5's 2-barrier/tile variant measured only 32% MfmaUtil):
//   each phase p: { ds_read frags(p); stage 2 quarters(kt+1);
//                   s_barrier; lgkmcnt(0); sched_barrier;
//                   setprio(1) 16xMFMA setprio(0); [vmcnt publish]; s_barrier }
// Phases: P0(ks0,i0-3: 8 reads, stage Bq0,Bq1) P1(ks0,i4-7: 4 reads, Bq2,Bq3)
//         P2(ks1,i0-3: 8 reads, Aq0,Aq2)       P3(ks1,i4-7: 4 reads, Aq1,Aq3)
// Counted publishes (T4 — never drained mid-loop), FIFO accounting:
//   end-P0: outstanding {Aq1,Aq3(kt), Bq0,Bq1(kt+1)} = 4 -> vmcnt(2) lands
//           Aq13(kt), needed by P1(kt) reads. Last tile: vmcnt(0) (2 loads, old).
//   end-P3: outstanding = 8 loads of tile kt+1 -> vmcnt(2) lands Bq0-3,Aq0,Aq2,
//           exactly what P0(kt+1) reads; Aq1,Aq3(kt+1) stay in flight.
// vmcnt is wave-local -> each publish bounds own loads THEN barriers (all waves'
// loads counted at the same program point => staged data globally visible).
// Buffer-reuse hazard: every wave's reads of buf[b] complete at its own
// pre-MFMA lgkm(0) in that phase, strictly before the end-P3 barrier that
// precedes any DMA overwriting buf[b] two K-tiles later.
// Int32 accumulation, per-element K-order unchanged -> bit-identical C.
#define MFMA_I8(i, j, av, bv) \
  acc[i][j] = __builtin_amdgcn_mfma_i32_16x16x64_i8(av, bv, acc[i][j], 0, 0, 0)

#define MFMA16(IB) \
  __builtin_amdgcn_s_setprio(1); \
  MFMA_I8(IB + 0, 0, a0, b0); MFMA_I8(IB + 0, 1, a0, b1); MFMA_I8(IB + 0, 2, a0, b2); MFMA_I8(IB + 0, 3, a0, b3); \
  MFMA_I8(IB + 1, 0, a1, b0); MFMA_I8(IB + 1, 1, a1, b1); MFMA_I8(IB + 1, 2, a1, b2); MFMA_I8(IB + 1, 3, a1, b3); \
  MFMA_I8(IB + 2, 0, a2, b0); MFMA_I8(IB + 2, 1, a2, b1); MFMA_I8(IB + 2, 2, a2, b2); MFMA_I8(IB + 2, 3, a2, b3); \
  MFMA_I8(IB + 3, 0, a3, b0); MFMA_I8(IB + 3, 1, a3, b1); MFMA_I8(IB + 3, 2, a3, b2); MFMA_I8(IB + 3, 3, a3, b3); \
  __builtin_amdgcn_s_setprio(0)

#define PRE_MFMA() \
  __builtin_amdgcn_s_barrier(); \
  asm volatile("s_waitcnt lgkmcnt(0)" ::: "memory"); \
  __builtin_amdgcn_sched_barrier(0)

template <int LDA_, int LDB_, int KT>
__device__ __forceinline__ void gemm_core4p(const char* __restrict__ A,
                                            const char* __restrict__ B,
                                            int mBase, int nBase,
                                            char* __restrict__ smem,
                                            int4v acc[8][4]) {
  const int t = threadIdx.x;          // 0..511
  const int lane = t & 63;
  const int w = t >> 6;               // wave 0..7
  const int wm = w & 1;               // rows wm*128
  const int wn = w >> 1;              // cols wn*64
  // staging map: thread t -> row-in-quarter sRow=t>>3, swizzled k-seg sSeg
  const int sRow = t >> 3;            // 0..63
  const int sSeg = (t & 7) ^ (sRow & 7);
  const char* Ag = A + (size_t)(mBase + sRow) * LDA_ + sSeg * 16;
  const char* Bg = B + (size_t)(nBase + sRow) * LDB_ + sSeg * 16;
  // fragment map
  const int q  = lane >> 4;
  const int fr = lane & 15;
  const int sw = fr & 7;
  const int s0 = ((q) ^ sw) << 4;       // ks=0 slot
  const int s1 = ((4 + q) ^ sw) << 4;   // ks=1 slot
  const int rA = wm * 128 + fr;
  const int rB = wn * 64 + fr;
  const int dst = t << 4;             // linear LDS slot within an 8KB quarter

  // quarter stage helpers (Q*64 rows source offset; Q*8192 LDS offset)
#define STG_A(Q, KTI, BUFO) \
  ldg_lds16(Ag + (size_t)((Q) * 64) * LDA_ + (size_t)(KTI) * 128, \
            smem + (BUFO) + (Q) * 8192 + dst)
#define STG_B(Q, KTI, BUFO) \
  ldg_lds16(Bg + (size_t)((Q) * 64) * LDB_ + (size_t)(KTI) * 128, \
            smem + (BUFO) + 32768 + (Q) * 8192 + dst)

  // prologue: tile 0 in steady-state FIFO order (B first, Aq02, Aq13 last)
  STG_B(0, 0, 0); STG_B(1, 0, 0); STG_B(2, 0, 0); STG_B(3, 0, 0);
  STG_A(0, 0, 0); STG_A(2, 0, 0); STG_A(1, 0, 0); STG_A(3, 0, 0);
  asm volatile("s_waitcnt vmcnt(2)\n\ts_barrier" ::: "memory");

  int cur = 0;
  for (int kt = 0; kt < KT; ++kt) {
    const int nxt = cur ^ 65536;
    const char* Ab = smem + cur;
    const char* Bb = smem + cur + 32768;
    int4v a0, a1, a2, a3, b0, b1, b2, b3;
    // ---- P0: ks=0, i=0..3 ----
    a0 = *(const int4v*)(Ab + (rA +  0) * 128 + s0);
    a1 = *(const int4v*)(Ab + (rA + 16) * 128 + s0);
    a2 = *(const int4v*)(Ab + (rA + 32) * 128 + s0);
    a3 = *(const int4v*)(Ab + (rA + 48) * 128 + s0);
    b0 = *(const int4v*)(Bb + (rB +  0) * 128 + s0);
    b1 = *(const int4v*)(Bb + (rB + 16) * 128 + s0);
    b2 = *(const int4v*)(Bb + (rB + 32) * 128 + s0);
    b3 = *(const int4v*)(Bb + (rB + 48) * 128 + s0);
    if (kt + 1 < KT) { STG_B(0, kt + 1, nxt); STG_B(1, kt + 1, nxt); }
    PRE_MFMA();
    MFMA16(0);
    if (kt + 1 < KT) { asm volatile("s_waitcnt vmcnt(2)" ::: "memory"); }
    else             { asm volatile("s_waitcnt vmcnt(0)" ::: "memory"); }
    __builtin_amdgcn_s_barrier();
    // ---- P1: ks=0, i=4..7 (b0..b3 reused from registers) ----
    a0 = *(const int4v*)(Ab + (rA +  64) * 128 + s0);
    a1 = *(const int4v*)(Ab + (rA +  80) * 128 + s0);
    a2 = *(const int4v*)(Ab + (rA +  96) * 128 + s0);
    a3 = *(const int4v*)(Ab + (rA + 112) * 128 + s0);
    if (kt + 1 < KT) { STG_B(2, kt + 1, nxt); STG_B(3, kt + 1, nxt); }
    PRE_MFMA();
    MFMA16(4);
    __builtin_amdgcn_s_barrier();
    // ---- P2: ks=1, i=0..3 ----
    a0 = *(const int4v*)(Ab + (rA +  0) * 128 + s1);
    a1 = *(const int4v*)(Ab + (rA + 16) * 128 + s1);
    a2 = *(const int4v*)(Ab + (rA + 32) * 128 + s1);
    a3 = *(const int4v*)(Ab + (rA + 48) * 128 + s1);
    b0 = *(const int4v*)(Bb + (rB +  0) * 128 + s1);
    b1 = *(const int4v*)(Bb + (rB + 16) * 128 + s1);
    b2 = *(const int4v*)(Bb + (rB + 32) * 128 + s1);
    b3 = *(const int4v*)(Bb + (rB + 48) * 128 + s1);
    if (kt + 1 < KT) { STG_A(0, kt + 1, nxt); STG_A(2, kt + 1, nxt); }
    PRE_MFMA();
    MFMA16(0);
    __builtin_amdgcn_s_barrier();
    // ---- P3: ks=1, i=4..7 ----
    a0 = *(const int4v*)(Ab + (rA +  64) * 128 + s1);
    a1 = *(const int4v*)(Ab + (rA +  80) * 128 + s1);
    a2 = *(const int4v*)(Ab + (rA +  96) * 128 + s1);
    a3 = *(const int4v*)(Ab + (rA + 112) * 128 + s1);
    if (kt + 1 < KT) { STG_A(1, kt + 1, nxt); STG_A(3, kt + 1, nxt); }
    PRE_MFMA();
    MFMA16(4);
    asm volatile("s_waitcnt vmcnt(2)" ::: "memory");
    __builtin_amdgcn_s_barrier();
    cur = nxt;
  }
#undef STG_A
#undef STG_B
}

// ---------------- K5: GEMM1 + relu^2 -> h2(fp16) + row-max partials ----------------
// grid: (x = m-blocks(64), y = n-blocks(16)) — m-fastest for L2 B-panel sharing
__global__ __launch_bounds__(512, 2) void k_gemm1(const char* __restrict__ xq,
                                                  const char* __restrict__ wq,
                                                  const float* __restrict__ wsc,
                                                  const float* __restrict__ dqx,
                                                  __half* __restrict__ h2,
                                                  float* __restrict__ pmax) {
  __shared__ char smem[131072];
  int4v acc[8][4];
#pragma unroll
  for (int i = 0; i < 8; ++i)
#pragma unroll
    for (int j = 0; j < 4; ++j) acc[i][j] = (int4v){0, 0, 0, 0};
  const int mBase = blockIdx.x * 256;
  const int nBase = blockIdx.y * 256;
  gemm_core4p<H_DIM, H_DIM, 8>(xq, wq, mBase, nBase, smem, acc);

  const int t = threadIdx.x;
  const int lane = t & 63;
  const int w = t >> 6;
  const int wm = w & 1;
  const int wn = w >> 1;
  const int q  = lane >> 4;
  const int fr = lane & 15;
  const float dqw = wsc[0];
#pragma unroll
  for (int i = 0; i < 8; ++i) {
    const int rbase = mBase + wm * 128 + i * 16 + (q << 2);
    const float4 dq4 = *(const float4*)(dqx + rbase);
    const float* dqp = (const float*)&dq4;
    float rmax[4] = {0.0f, 0.0f, 0.0f, 0.0f};
#pragma unroll
    for (int j = 0; j < 4; ++j) {
      const int col = nBase + wn * 64 + j * 16 + fr;
#pragma unroll
      for (int r = 0; r < 4; ++r) {
        float v = (float)acc[i][j][r] * dqp[r] * dqw;
        v = fmaxf(v, 0.0f);
        v = v * v;
        const __half h = __float2half(v);
        h2[(size_t)(rbase + r) * F_DIM + col] = h;
        rmax[r] = fmaxf(rmax[r], __half2float(h));
      }
    }
#pragma unroll
    for (int s = 1; s < 16; s <<= 1) {
#pragma unroll
      for (int r = 0; r < 4; ++r) rmax[r] = fmaxf(rmax[r], __shfl_xor(rmax[r], s, 64));
    }
    if (fr == 0) {
      const int nb2 = blockIdx.y * 4 + wn;   // 64-col group, 16*4 = 64 groups
#pragma unroll
      for (int r = 0; r < 4; ++r) pmax[(size_t)nb2 * M_TOK + rbase + r] = rmax[r];
    }
  }
}

// ---------------- K5b: fused row-max reduce + quantize h2 -> q2 ----------------
__global__ __launch_bounds__(256) void k_quant2(const __half* __restrict__ h2,
                                                const float* __restrict__ pmax,
                                                char* __restrict__ q2,
                                                float* __restrict__ dq2) {
  const int row = blockIdx.x;
  const int t = threadIdx.x;
  __shared__ float sm;
  if (t < 64) {
    float m = pmax[(size_t)t * M_TOK + row];
#pragma unroll
    for (int sh = 32; sh; sh >>= 1) m = fmaxf(m, __shfl_xor(m, sh, 64));
    if (t == 0) sm = fmaxf(m, 1e-5f);
  }
  __syncthreads();
  const float mx = sm;
  const float s = 127.0f / mx;
  if (t == 0) dq2[row] = mx * (1.0f / 127.0f);
  const size_t i = (size_t)row * F_DIM + t * 16;
  __half2 hh[8];
  *(float4*)(hh)     = *(const float4*)(h2 + i);
  *(float4*)(hh + 4) = *(const float4*)(h2 + i + 8);
  unsigned u[4];
#pragma unroll
  for (int k = 0; k < 4; ++k) {
    const int q0 = (int)rintf(fminf(__low2float(hh[2 * k]) * s, 127.0f));
    const int q1 = (int)rintf(fminf(__high2float(hh[2 * k]) * s, 127.0f));
    const int q2i = (int)rintf(fminf(__low2float(hh[2 * k + 1]) * s, 127.0f));
    const int q3 = (int)rintf(fminf(__high2float(hh[2 * k + 1]) * s, 127.0f));
    u[k] = (q0 & 255) | ((q1 & 255) << 8) | ((q2i & 255) << 16) | ((q3 & 255) << 24);
  }
  *(uint4*)(q2 + i) = make_uint4(u[0], u[1], u[2], u[3]);
}

// ---------------- K6: GEMM2 + dequant + residual ----------------
// grid: (x = m-blocks(64), y = n-blocks(4)) = 256 blocks = 1/CU
__global__ __launch_bounds__(512, 2) void k_gemm2(const char* __restrict__ q2,
                                                  const char* __restrict__ wq,
                                                  const float* __restrict__ wsc,
                                                  const float* __restrict__ dq2,
                                                  const float* __restrict__ x,
                                                  float* __restrict__ out) {
  __shared__ char smem[131072];
  int4v acc[8][4];
#pragma unroll
  for (int i = 0; i < 8; ++i)
#pragma unroll
    for (int j = 0; j < 4; ++j) acc[i][j] = (int4v){0, 0, 0, 0};
  const int mBase = blockIdx.x * 256;
  const int nBase = blockIdx.y * 256;
  gemm_core4p<F_DIM, F_DIM, 32>(q2, wq, mBase, nBase, smem, acc);

  const int t = threadIdx.x;
  const int lane = t & 63;
  const int w = t >> 6;
  const int wm = w & 1;
  const int wn = w >> 1;
  const int q  = lane >> 4;
  const int fr = lane & 15;
  const float dqw = wsc[2];
#pragma unroll
  for (int i = 0; i < 8; ++i) {
    const int rbase = mBase + wm * 128 + i * 16 + (q << 2);
    const float4 dq4 = *(const float4*)(dq2 + rbase);
    const float* dqp = (const float*)&dq4;
#pragma unroll
    for (int j = 0; j < 4; ++j) {
      const int col = nBase + wn * 64 + j * 16 + fr;
#pragma unroll
      for (int r = 0; r < 4; ++r) {
        const size_t idx = (size_t)(rbase + r) * H_DIM + col;
        out[idx] = (float)acc[i][j][r] * dqp[r] * dqw + x[idx];
      }
    }
  }
}

extern "C" void kernel_launch(void* const* d_in, const int* in_sizes, int n_in,
                              void* d_out, int out_size, void* d_ws, size_t ws_size,
                              hipStream_t stream) {
  const float* x  = (const float*)d_in[0];
  const float* nw = (const float*)d_in[1];
  const float* wu = (const float*)d_in[2];
  const float* wd = (const float*)d_in[3];
  float* out = (float*)d_out;
  char* ws = (char*)d_ws;
  if (ws_size < WS_NEEDED) return;  // workspace too small: leave output poisoned (diagnostic)

  __half* h2     = (__half*)(ws + OFF_H2);
  char* q2       = ws + OFF_Q2;
  char* xq       = ws + OFF_XQ;
  char* wqu      = ws + OFF_WQU;
  char* wqd      = ws + OFF_WQD;
  float* dqx     = (float*)(ws + OFF_DQX);
  float* dq2     = (float*)(ws + OFF_DQ2);
  float* pmax    = (float*)(ws + OFF_PMAX);
  float* wpart   = (float*)(ws + OFF_WPART);
  float* wsc     = (float*)(ws + OFF_WSC);

  k_wabs<<<2048, 256, 0, stream>>>(wu, wd, wpart);
  k_wscale<<<2, 256, 0, stream>>>(wpart, wsc);
  k_wquant<<<8192, 256, 0, stream>>>(wu, wd, wqu, wqd, wsc);
  k_rmsnorm_quant<<<M_TOK, 256, 0, stream>>>(x, nw, xq, dqx);
  k_gemm1<<<dim3(M_TOK / 256, F_DIM / 256), 512, 0, stream>>>(xq, wqu, wsc, dqx, h2, pmax);
  k_quant2<<<M_TOK, 256, 0, stream>>>(h2, pmax, q2, dq2);
  k_gemm2<<<dim3(M_TOK / 256, H_DIM / 256), 512, 0, stream>>>(q2, wqd, wsc, dq2, x, out);
}

// Round 9
// 333.962 us; speedup vs baseline: 1.0159x; 1.0159x over previous
//
#include <hip/hip_runtime.h>
#include <hip/hip_fp16.h>

#define M_TOK 16384
#define H_DIM 1024
#define F_DIM 4096

typedef __attribute__((ext_vector_type(4))) int int4v;
typedef __attribute__((ext_vector_type(4))) float f32x4;

// ---------------- workspace layout (bytes) ----------------
static const size_t OFF_H2    = 0;                       // fp16 [M,F]  134,217,728
static const size_t OFF_RS2   = OFF_H2   + 134217728ULL; // f32 [M] (reuses old q2 slot)
static const size_t OFF_XQ    = OFF_RS2  + 67108864ULL;  // int8 [M,H]   16,777,216
static const size_t OFF_WQU   = OFF_XQ   + 16777216ULL;  // int8 [F,H]    4,194,304
static const size_t OFF_WQD   = OFF_WQU  + 4194304ULL;   // int8 [H,F]    4,194,304
static const size_t OFF_DQX   = OFF_WQD  + 4194304ULL;   // f32 [M]          65,536
static const size_t OFF_DQ2   = OFF_DQX  + 65536ULL;     // f32 [M]          65,536
static const size_t OFF_PMAX  = OFF_DQ2  + 65536ULL;     // f32 [64,M]    4,194,304
static const size_t OFF_WPART = OFF_PMAX + 4194304ULL;   // f32 [2048]        8,192
static const size_t OFF_WSC   = OFF_WPART+ 8192ULL;      // f32 [4]
static const size_t WS_NEEDED = OFF_WSC  + 16ULL;

__device__ __forceinline__ void ldg_lds16(const void* g, void* l) {
  __builtin_amdgcn_global_load_lds(
      (const __attribute__((address_space(1))) void*)g,
      (__attribute__((address_space(3))) void*)l, 16, 0, 0);
}

// 32-byte global load as 2x dwordx4 via asm: pinned program order so the vmcnt
// FIFO accounting below stays exact (compiler cannot sink/hoist these).
__device__ __forceinline__ void gload32(const void* p, f32x4& a, f32x4& b) {
  asm volatile("global_load_dwordx4 %0, %2, off\n\t"
               "global_load_dwordx4 %1, %2, off offset:16"
               : "=&v"(a), "=&v"(b) : "v"(p) : "memory");
}

// ---------------- K1: |w| partial sums (deterministic) ----------------
__global__ __launch_bounds__(256) void k_wabs(const float* __restrict__ wu,
                                              const float* __restrict__ wd,
                                              float* __restrict__ part) {
  const int b = blockIdx.x;                 // 0..2047 (1024 per tensor)
  const float* w = (b < 1024) ? wu : wd;
  const int cb = b & 1023;
  const size_t base = (size_t)cb * 4096 + threadIdx.x * 4;
  float s = 0.0f;
#pragma unroll
  for (int it = 0; it < 4; ++it) {
    const float4 v = *(const float4*)(w + base + it * 1024);
    s += fabsf(v.x) + fabsf(v.y) + fabsf(v.z) + fabsf(v.w);
  }
#pragma unroll
  for (int sh = 32; sh; sh >>= 1) s += __shfl_xor(s, sh, 64);
  __shared__ float red[4];
  if ((threadIdx.x & 63) == 0) red[threadIdx.x >> 6] = s;
  __syncthreads();
  if (threadIdx.x == 0) part[b] = red[0] + red[1] + red[2] + red[3];
}

// ---------------- K2: finalize per-tensor scale ----------------
__global__ __launch_bounds__(256) void k_wscale(const float* __restrict__ part,
                                                float* __restrict__ wsc) {
  const int b = blockIdx.x;                 // 0: w_up, 1: w_down
  const float* p = part + b * 1024;
  float s = p[threadIdx.x] + p[threadIdx.x + 256] + p[threadIdx.x + 512] + p[threadIdx.x + 768];
#pragma unroll
  for (int sh = 32; sh; sh >>= 1) s += __shfl_xor(s, sh, 64);
  __shared__ float red[4];
  if ((threadIdx.x & 63) == 0) red[threadIdx.x >> 6] = s;
  __syncthreads();
  if (threadIdx.x == 0) {
    const float mean = (red[0] + red[1] + red[2] + red[3]) * (1.0f / 4194304.0f);
    const float c = fmaxf(mean, 1e-5f);
    wsc[b * 2]     = c;         // dequant factor (1/scale)
    wsc[b * 2 + 1] = 1.0f / c;  // scale
  }
}

// ---------------- K3: ternary-quantize both weights ----------------
__global__ __launch_bounds__(256) void k_wquant(const float* __restrict__ wu,
                                                const float* __restrict__ wd,
                                                char* __restrict__ qu,
                                                char* __restrict__ qd,
                                                const float* __restrict__ wsc) {
  const size_t t = (size_t)blockIdx.x * 256 + threadIdx.x;  // 0..2097151
  const float* w; char* q; float scale; size_t i;
  if (t < 1048576) { w = wu; q = qu; scale = wsc[1]; i = t * 4; }
  else             { w = wd; q = qd; scale = wsc[3]; i = (t - 1048576) * 4; }
  const float4 v = *(const float4*)(w + i);
  const int a = (int)rintf(fminf(fmaxf(v.x * scale, -1.0f), 1.0f));
  const int b = (int)rintf(fminf(fmaxf(v.y * scale, -1.0f), 1.0f));
  const int c = (int)rintf(fminf(fmaxf(v.z * scale, -1.0f), 1.0f));
  const int d = (int)rintf(fminf(fmaxf(v.w * scale, -1.0f), 1.0f));
  *(unsigned*)(q + i) = (a & 255) | ((b & 255) << 8) | ((c & 255) << 16) | ((d & 255) << 24);
}

// ---------------- K4: fused RMSNorm + act_quant ----------------
__global__ __launch_bounds__(256) void k_rmsnorm_quant(const float* __restrict__ x,
                                                       const float* __restrict__ nw,
                                                       char* __restrict__ xq,
                                                       float* __restrict__ dqx) {
  const int row = blockIdx.x;
  const int t = threadIdx.x;
  const float4 v = *(const float4*)(x + (size_t)row * H_DIM + t * 4);
  float ss = v.x * v.x + v.y * v.y + v.z * v.z + v.w * v.w;
#pragma unroll
  for (int sh = 32; sh; sh >>= 1) ss += __shfl_xor(ss, sh, 64);
  __shared__ float red[4];
  __shared__ float redm[4];
  if ((t & 63) == 0) red[t >> 6] = ss;
  __syncthreads();
  ss = red[0] + red[1] + red[2] + red[3];
  const float rinv = 1.0f / sqrtf(ss * (1.0f / 1024.0f) + 1e-6f);
  const float4 w4 = *(const float4*)(nw + t * 4);
  float4 n;
  n.x = v.x * rinv * w4.x;  n.y = v.y * rinv * w4.y;
  n.z = v.z * rinv * w4.z;  n.w = v.w * rinv * w4.w;
  float am = fmaxf(fmaxf(fabsf(n.x), fabsf(n.y)), fmaxf(fabsf(n.z), fabsf(n.w)));
#pragma unroll
  for (int sh = 32; sh; sh >>= 1) am = fmaxf(am, __shfl_xor(am, sh, 64));
  if ((t & 63) == 0) redm[t >> 6] = am;
  __syncthreads();
  am = fmaxf(fmaxf(redm[0], redm[1]), fmaxf(redm[2], redm[3]));
  am = fmaxf(am, 1e-5f);
  const float scale = 127.0f / am;
  const int qa = (int)rintf(fminf(fmaxf(n.x * scale, -128.0f), 127.0f));
  const int qb = (int)rintf(fminf(fmaxf(n.y * scale, -128.0f), 127.0f));
  const int qc = (int)rintf(fminf(fmaxf(n.z * scale, -128.0f), 127.0f));
  const int qd = (int)rintf(fminf(fmaxf(n.w * scale, -128.0f), 127.0f));
  *(unsigned*)(xq + (size_t)row * H_DIM + t * 4) =
      (qa & 255) | ((qb & 255) << 8) | ((qc & 255) << 16) | ((qd & 255) << 24);
  if (t == 0) dqx[row] = am * (1.0f / 127.0f);
}

// ---------------- shared int8 GEMM core (gemm1): 256x256, BK=128 — round-5 verbatim ----
// Best measured variant (86.7 us, MfmaUtil 32%, 0 bank conflicts). See r5 notes.
#define MFMA_I8(i, j, av, bv) \
  acc[i][j] = __builtin_amdgcn_mfma_i32_16x16x64_i8(av, bv, acc[i][j], 0, 0, 0)

#define MFMA16(IB) \
  __builtin_amdgcn_s_setprio(1); \
  MFMA_I8(IB + 0, 0, a0, b0); MFMA_I8(IB + 0, 1, a0, b1); MFMA_I8(IB + 0, 2, a0, b2); MFMA_I8(IB + 0, 3, a0, b3); \
  MFMA_I8(IB + 1, 0, a1, b0); MFMA_I8(IB + 1, 1, a1, b1); MFMA_I8(IB + 1, 2, a1, b2); MFMA_I8(IB + 1, 3, a1, b3); \
  MFMA_I8(IB + 2, 0, a2, b0); MFMA_I8(IB + 2, 1, a2, b1); MFMA_I8(IB + 2, 2, a2, b2); MFMA_I8(IB + 2, 3, a2, b3); \
  MFMA_I8(IB + 3, 0, a3, b0); MFMA_I8(IB + 3, 1, a3, b1); MFMA_I8(IB + 3, 2, a3, b2); MFMA_I8(IB + 3, 3, a3, b3); \
  __builtin_amdgcn_s_setprio(0)

template <int LDA_, int LDB_, int KT>
__device__ __forceinline__ void gemm_core4p(const char* __restrict__ A,
                                            const char* __restrict__ B,
                                            int mBase, int nBase,
                                            char* __restrict__ smem,
                                            int4v acc[8][4]) {
  const int t = threadIdx.x;          // 0..511
  const int lane = t & 63;
  const int w = t >> 6;               // wave 0..7
  const int wm = w & 1;               // rows wm*128
  const int wn = w >> 1;              // cols wn*64
  const int sRow = t >> 3;            // 0..63
  const int sSeg = (t & 7) ^ (sRow & 7);
  const char* Ag = A + (size_t)(mBase + sRow) * LDA_ + sSeg * 16;
  const char* Bg = B + (size_t)(nBase + sRow) * LDB_ + sSeg * 16;
  const int q  = lane >> 4;
  const int fr = lane & 15;
  const int sw = fr & 7;
  const int s0 = ((q) ^ sw) << 4;       // ks=0 slot
  const int s1 = ((4 + q) ^ sw) << 4;   // ks=1 slot
  const int rA = wm * 128 + fr;
  const int rB = wn * 64 + fr;
  const int dst = t << 4;

#define STG_A(Q, KTI, BUFO) \
  ldg_lds16(Ag + (size_t)((Q) * 64) * LDA_ + (size_t)(KTI) * 128, \
            smem + (BUFO) + (Q) * 8192 + dst)
#define STG_B(Q, KTI, BUFO) \
  ldg_lds16(Bg + (size_t)((Q) * 64) * LDB_ + (size_t)(KTI) * 128, \
            smem + (BUFO) + 32768 + (Q) * 8192 + dst)

  STG_B(0, 0, 0); STG_B(1, 0, 0); STG_B(2, 0, 0); STG_B(3, 0, 0);
  STG_A(0, 0, 0); STG_A(2, 0, 0); STG_A(1, 0, 0); STG_A(3, 0, 0);
  asm volatile("s_waitcnt vmcnt(2)\n\ts_barrier" ::: "memory");

  int cur = 0;
  for (int kt = 0; kt < KT; ++kt) {
    const int nxt = cur ^ 65536;
    const char* Ab = smem + cur;
    const char* Bb = smem + cur + 32768;
    int4v a0, a1, a2, a3, b0, b1, b2, b3;
    // ---- P0 ----
    a0 = *(const int4v*)(Ab + (rA +  0) * 128 + s0);
    a1 = *(const int4v*)(Ab + (rA + 16) * 128 + s0);
    a2 = *(const int4v*)(Ab + (rA + 32) * 128 + s0);
    a3 = *(const int4v*)(Ab + (rA + 48) * 128 + s0);
    b0 = *(const int4v*)(Bb + (rB +  0) * 128 + s0);
    b1 = *(const int4v*)(Bb + (rB + 16) * 128 + s0);
    b2 = *(const int4v*)(Bb + (rB + 32) * 128 + s0);
    b3 = *(const int4v*)(Bb + (rB + 48) * 128 + s0);
    if (kt + 1 < KT) { STG_B(0, kt + 1, nxt); STG_B(1, kt + 1, nxt); }
    MFMA16(0);
    if (kt + 1 < KT) { asm volatile("s_waitcnt vmcnt(2)\n\ts_barrier" ::: "memory"); }
    else             { asm volatile("s_waitcnt vmcnt(0)\n\ts_barrier" ::: "memory"); }
    // ---- P1 ----
    a0 = *(const int4v*)(Ab + (rA +  64) * 128 + s0);
    a1 = *(const int4v*)(Ab + (rA +  80) * 128 + s0);
    a2 = *(const int4v*)(Ab + (rA +  96) * 128 + s0);
    a3 = *(const int4v*)(Ab + (rA + 112) * 128 + s0);
    if (kt + 1 < KT) { STG_B(2, kt + 1, nxt); STG_B(3, kt + 1, nxt); }
    MFMA16(4);
    // ---- P2 ----
    a0 = *(const int4v*)(Ab + (rA +  0) * 128 + s1);
    a1 = *(const int4v*)(Ab + (rA + 16) * 128 + s1);
    a2 = *(const int4v*)(Ab + (rA + 32) * 128 + s1);
    a3 = *(const int4v*)(Ab + (rA + 48) * 128 + s1);
    b0 = *(const int4v*)(Bb + (rB +  0) * 128 + s1);
    b1 = *(const int4v*)(Bb + (rB + 16) * 128 + s1);
    b2 = *(const int4v*)(Bb + (rB + 32) * 128 + s1);
    b3 = *(const int4v*)(Bb + (rB + 48) * 128 + s1);
    if (kt + 1 < KT) { STG_A(0, kt + 1, nxt); STG_A(2, kt + 1, nxt); }
    MFMA16(0);
    // ---- P3 ----
    a0 = *(const int4v*)(Ab + (rA +  64) * 128 + s1);
    a1 = *(const int4v*)(Ab + (rA +  80) * 128 + s1);
    a2 = *(const int4v*)(Ab + (rA +  96) * 128 + s1);
    a3 = *(const int4v*)(Ab + (rA + 112) * 128 + s1);
    if (kt + 1 < KT) { STG_A(1, kt + 1, nxt); STG_A(3, kt + 1, nxt); }
    MFMA16(4);
    asm volatile("s_waitcnt vmcnt(2)\n\ts_barrier" ::: "memory");
    cur = nxt;
  }
#undef STG_A
#undef STG_B
}

// ---------------- K5: GEMM1 + relu^2 -> h2(fp16) + row-max partials ----------------
__global__ __launch_bounds__(512, 2) void k_gemm1(const char* __restrict__ xq,
                                                  const char* __restrict__ wq,
                                                  const float* __restrict__ wsc,
                                                  const float* __restrict__ dqx,
                                                  __half* __restrict__ h2,
                                                  float* __restrict__ pmax) {
  __shared__ char smem[131072];
  int4v acc[8][4];
#pragma unroll
  for (int i = 0; i < 8; ++i)
#pragma unroll
    for (int j = 0; j < 4; ++j) acc[i][j] = (int4v){0, 0, 0, 0};
  const int mBase = blockIdx.x * 256;
  const int nBase = blockIdx.y * 256;
  gemm_core4p<H_DIM, H_DIM, 8>(xq, wq, mBase, nBase, smem, acc);

  const int t = threadIdx.x;
  const int lane = t & 63;
  const int w = t >> 6;
  const int wm = w & 1;
  const int wn = w >> 1;
  const int q  = lane >> 4;
  const int fr = lane & 15;
  const float dqw = wsc[0];
#pragma unroll
  for (int i = 0; i < 8; ++i) {
    const int rbase = mBase + wm * 128 + i * 16 + (q << 2);
    const float4 dq4 = *(const float4*)(dqx + rbase);
    const float* dqp = (const float*)&dq4;
    float rmax[4] = {0.0f, 0.0f, 0.0f, 0.0f};
#pragma unroll
    for (int j = 0; j < 4; ++j) {
      const int col = nBase + wn * 64 + j * 16 + fr;
#pragma unroll
      for (int r = 0; r < 4; ++r) {
        float v = (float)acc[i][j][r] * dqp[r] * dqw;
        v = fmaxf(v, 0.0f);
        v = v * v;
        const __half h = __float2half(v);
        h2[(size_t)(rbase + r) * F_DIM + col] = h;
        rmax[r] = fmaxf(rmax[r], __half2float(h));
      }
    }
#pragma unroll
    for (int s = 1; s < 16; s <<= 1) {
#pragma unroll
      for (int r = 0; r < 4; ++r) rmax[r] = fmaxf(rmax[r], __shfl_xor(rmax[r], s, 64));
    }
    if (fr == 0) {
      const int nb2 = blockIdx.y * 4 + wn;
#pragma unroll
      for (int r = 0; r < 4; ++r) pmax[(size_t)nb2 * M_TOK + rbase + r] = rmax[r];
    }
  }
}

// ---------------- K5b: per-row scale from pmax (replaces the 205MB quant2 pass) -------
__global__ __launch_bounds__(256) void k_rowscale(const float* __restrict__ pmax,
                                                  float* __restrict__ dq2,
                                                  float* __restrict__ rs2) {
  const int row = blockIdx.x * 256 + threadIdx.x;
  float m = 0.0f;
#pragma unroll
  for (int p = 0; p < 64; ++p) m = fmaxf(m, pmax[(size_t)p * M_TOK + row]);
  m = fmaxf(m, 1e-5f);
  dq2[row] = m * (1.0f / 127.0f);
  rs2[row] = 127.0f / m;
}

// quantize 16 fp16 (2 f32x4 raw bits) -> 16 int8, identical math to old k_quant2:
// q = rint(min(v*s, 127)), v >= 0 (relu^2 output).
__device__ __forceinline__ void cvt_write_q(const f32x4& va, const f32x4& vb,
                                            float s, char* d) {
  union { f32x4 f[2]; __half2 h[8]; } u;
  u.f[0] = va; u.f[1] = vb;
  unsigned o[4];
#pragma unroll
  for (int p = 0; p < 4; ++p) {
    const float f0 = __low2float(u.h[2 * p]);
    const float f1 = __high2float(u.h[2 * p]);
    const float f2 = __low2float(u.h[2 * p + 1]);
    const float f3 = __high2float(u.h[2 * p + 1]);
    const int q0 = (int)rintf(fminf(f0 * s, 127.0f));
    const int q1 = (int)rintf(fminf(f1 * s, 127.0f));
    const int q2 = (int)rintf(fminf(f2 * s, 127.0f));
    const int q3 = (int)rintf(fminf(f3 * s, 127.0f));
    o[p] = (q0 & 255) | ((q1 & 255) << 8) | ((q2 & 255) << 16) | ((q3 & 255) << 24);
  }
  *(uint4*)d = make_uint4(o[0], o[1], o[2], o[3]);
}

// ---------------- gemm2 core: fused on-the-fly act-quant of A (h2 fp16 -> int8) -------
// Same 256x256/BK=128 geometry+conflict-free layout as gemm_core4p. B staged via DMA;
// A reg-staged (T14 issue-early/write-late, counted vmcnt FIFO).
//
// Correctness structure (audited r8/r9):
//  (a) prologue lands tile0 A with vmcnt(4), converts directly, THEN issues
//      tile1-q01 into a01 (prior loads retired -> no WAW, no in-flight reg copy).
//  (b) sched_barrier(0) after every counted vmcnt guarding reg-staged data
//      (rule #18: cvt VALU deps are on the gload asm, not the waitcnt asm).
//  (c) all s_barriers wave-uniform (conditions depend only on kt); no hang path.
//
// Steady state per tile kt (issue FIFO): [P0: B01-DMA(2), A-q23(kt+1)(4)]
// [P1: B23-DMA(2)] [P3: A-q01(kt+2)(4)]. Loop-entry outstanding = A-q01(kt+1) = 4.
//   P2(kt): vmcnt(8)+SB -> A-q01(kt+1) landed (issued P3(kt-1), ~5 phases cover);
//           convert+ds_write quarters 0,1 into nxt.
//   P3(kt): vmcnt(2)+SB -> A-q23(kt+1) landed (issued P0(kt), ~3 phases cover);
//           convert+ds_write quarters 2,3; issue A-q01(kt+2);
//           lgkmcnt(0) + vmcnt(4: B(kt+1) landed, newer = A-q01(kt+2)) + s_barrier
//           == tile kt+1 published. Single barrier/tile: reads hit cur only,
//           writes hit nxt only -> intra-tile wave skew is safe.
// Quantization math identical to old k_quant2 -> output bit-identical.
template <int KT>
__device__ __forceinline__ void gemm2_core(const __half* __restrict__ H,
                                           const char* __restrict__ B,
                                           const float* __restrict__ rs2,
                                           int mBase, int nBase,
                                           char* __restrict__ smem,
                                           int4v acc[8][4]) {
  const int t = threadIdx.x;
  const int lane = t & 63;
  const int w = t >> 6;
  const int wm = w & 1;
  const int wn = w >> 1;
  const int sRow = t >> 3;            // 0..63
  const int sSeg = (t & 7) ^ (sRow & 7);
  const __half* Hg = H + (size_t)(mBase + sRow) * F_DIM + sSeg * 16;  // half units
  const char*   Bg = B + (size_t)(nBase + sRow) * F_DIM + sSeg * 16;
  const int q  = lane >> 4;
  const int fr = lane & 15;
  const int sw = fr & 7;
  const int s0 = ((q) ^ sw) << 4;
  const int s1 = ((4 + q) ^ sw) << 4;
  const int rA = wm * 128 + fr;
  const int rB = wn * 64 + fr;
  const int dst = t << 4;

  // per-quarter row scales (rows invariant over kt) — load then drain FIFO clean
  float rs[4];
#pragma unroll
  for (int Q = 0; Q < 4; ++Q) rs[Q] = rs2[mBase + Q * 64 + sRow];
  asm volatile("s_waitcnt vmcnt(0)" ::: "memory");
  __builtin_amdgcn_sched_barrier(0);

#define STG_B2(Q, KTI, BUFO) \
  ldg_lds16(Bg + (size_t)((Q) * 64) * F_DIM + (size_t)(KTI) * 128, \
            smem + (BUFO) + 32768 + (Q) * 8192 + dst)
#define GLD_A(arr, i0, Q, KTI) \
  gload32(Hg + (size_t)(Q) * 64 * F_DIM + (size_t)(KTI) * 128, arr[i0], arr[i0 + 1])

  f32x4 a01[4];  // quarters 0,1 of next tile (issued P3, consumed P2)
  f32x4 a23[4];  // quarters 2,3 of next tile (issued P0, consumed P3)

  // prologue: tile0 A (8 loads) + tile0 B (4 DMA); land A; convert;
  // then issue tile1-q01 into a01 (prior a01 loads retired -> no WAW, no copy).
  GLD_A(a01, 0, 0, 0); GLD_A(a01, 2, 1, 0);
  GLD_A(a23, 0, 2, 0); GLD_A(a23, 2, 3, 0);
  STG_B2(0, 0, 0); STG_B2(1, 0, 0); STG_B2(2, 0, 0); STG_B2(3, 0, 0);
  asm volatile("s_waitcnt vmcnt(4)" ::: "memory");   // tile0 A landed; B(4) in flight
  __builtin_amdgcn_sched_barrier(0);
  cvt_write_q(a01[0], a01[1], rs[0], smem + 0 * 8192 + dst);
  cvt_write_q(a01[2], a01[3], rs[1], smem + 1 * 8192 + dst);
  cvt_write_q(a23[0], a23[1], rs[2], smem + 2 * 8192 + dst);
  cvt_write_q(a23[2], a23[3], rs[3], smem + 3 * 8192 + dst);
  GLD_A(a01, 0, 0, 1); GLD_A(a01, 2, 1, 1);          // tile1 q01
  asm volatile("s_waitcnt lgkmcnt(0)" ::: "memory"); // own ds_writes drained
  // publish tile0: B(0) landed (newer = A-q01(1) = 4 stays in flight)
  asm volatile("s_waitcnt vmcnt(4)\n\ts_barrier" ::: "memory");

  int cur = 0;
  for (int kt = 0; kt < KT; ++kt) {
    const int nxt = cur ^ 65536;
    const char* Ab = smem + cur;
    const char* Bb = smem + cur + 32768;
    int4v a0, a1, a2, a3, b0, b1, b2, b3;
    // ---- P0 ----
    a0 = *(const int4v*)(Ab + (rA +  0) * 128 + s0);
    a1 = *(const int4v*)(Ab + (rA + 16) * 128 + s0);
    a2 = *(const int4v*)(Ab + (rA + 32) * 128 + s0);
    a3 = *(const int4v*)(Ab + (rA + 48) * 128 + s0);
    b0 = *(const int4v*)(Bb + (rB +  0) * 128 + s0);
    b1 = *(const int4v*)(Bb + (rB + 16) * 128 + s0);
    b2 = *(const int4v*)(Bb + (rB + 32) * 128 + s0);
    b3 = *(const int4v*)(Bb + (rB + 48) * 128 + s0);
    if (kt + 1 < KT) {
      STG_B2(0, kt + 1, nxt); STG_B2(1, kt + 1, nxt);
      GLD_A(a23, 0, 2, kt + 1); GLD_A(a23, 2, 3, kt + 1);
    }
    MFMA16(0);
    // ---- P1 ----
    a0 = *(const int4v*)(Ab + (rA +  64) * 128 + s0);
    a1 = *(const int4v*)(Ab + (rA +  80) * 128 + s0);
    a2 = *(const int4v*)(Ab + (rA +  96) * 128 + s0);
    a3 = *(const int4v*)(Ab + (rA + 112) * 128 + s0);
    if (kt + 1 < KT) { STG_B2(2, kt + 1, nxt); STG_B2(3, kt + 1, nxt); }
    MFMA16(4);
    // ---- P2 ----
    a0 = *(const int4v*)(Ab + (rA +  0) * 128 + s1);
    a1 = *(const int4v*)(Ab + (rA + 16) * 128 + s1);
    a2 = *(const int4v*)(Ab + (rA + 32) * 128 + s1);
    a3 = *(const int4v*)(Ab + (rA + 48) * 128 + s1);
    b0 = *(const int4v*)(Bb + (rB +  0) * 128 + s1);
    b1 = *(const int4v*)(Bb + (rB + 16) * 128 + s1);
    b2 = *(const int4v*)(Bb + (rB + 32) * 128 + s1);
    b3 = *(const int4v*)(Bb + (rB + 48) * 128 + s1);
    if (kt + 1 < KT) {
      // A-q01(kt+1) landed: newer = B01(2)+A-q23(4)+B23(2) = 8
      asm volatile("s_waitcnt vmcnt(8)" ::: "memory");
      __builtin_amdgcn_sched_barrier(0);
      cvt_write_q(a01[0], a01[1], rs[0], smem + nxt + 0 * 8192 + dst);
      cvt_write_q(a01[2], a01[3], rs[1], smem + nxt + 1 * 8192 + dst);
    }
    MFMA16(0);
    // ---- P3 ----
    a0 = *(const int4v*)(Ab + (rA +  64) * 128 + s1);
    a1 = *(const int4v*)(Ab + (rA +  80) * 128 + s1);
    a2 = *(const int4v*)(Ab + (rA +  96) * 128 + s1);
    a3 = *(const int4v*)(Ab + (rA + 112) * 128 + s1);
    if (kt + 1 < KT) {
      // A-q23(kt+1) landed: newer = B23(2)
      asm volatile("s_waitcnt vmcnt(2)" ::: "memory");
      __builtin_amdgcn_sched_barrier(0);
      cvt_write_q(a23[0], a23[1], rs[2], smem + nxt + 2 * 8192 + dst);
      cvt_write_q(a23[2], a23[3], rs[3], smem + nxt + 3 * 8192 + dst);
    }
    if (kt + 2 < KT) { GLD_A(a01, 0, 0, kt + 2); GLD_A(a01, 2, 1, kt + 2); }
    MFMA16(4);
    if (kt + 1 < KT) {
      asm volatile("s_waitcnt lgkmcnt(0)" ::: "memory");   // ds_writes visible
      if (kt + 2 < KT) { asm volatile("s_waitcnt vmcnt(4)\n\ts_barrier" ::: "memory"); }
      else             { asm volatile("s_waitcnt vmcnt(0)\n\ts_barrier" ::: "memory"); }
    }
    cur = nxt;
  }
#undef STG_B2
#undef GLD_A
}

// ---------------- K6: GEMM2 (fused act-quant) + dequant + residual ----------------
// grid: (x = m-blocks(64), y = n-blocks(4)) = 256 blocks = 1/CU; same-x blocks share
// the h2 A-panel and land on the same XCD (lin%8 invariant over y since 64%8==0).
__global__ __launch_bounds__(512, 2) void k_gemm2(const __half* __restrict__ h2,
                                                  const char* __restrict__ wq,
                                                  const float* __restrict__ wsc,
                                                  const float* __restrict__ dq2,
                                                  const float* __restrict__ rs2,
                                                  const float* __restrict__ x,
                                                  float* __restrict__ out) {
  __shared__ char smem[131072];
  int4v acc[8][4];
#pragma unroll
  for (int i = 0; i < 8; ++i)
#pragma unroll
    for (int j = 0; j < 4; ++j) acc[i][j] = (int4v){0, 0, 0, 0};
  const int mBase = blockIdx.x * 256;
  const int nBase = blockIdx.y * 256;
  gemm2_core<32>(h2, wq, rs2, mBase, nBase, smem, acc);

  const int t = threadIdx.x;
  const int lane = t & 63;
  const int w = t >> 6;
  const int wm = w & 1;
  const int wn = w >> 1;
  const int q  = lane >> 4;
  const int fr = lane & 15;
  const float dqw = wsc[2];
#pragma unroll
  for (int i = 0; i < 8; ++i) {
    const int rbase = mBase + wm * 128 + i * 16 + (q << 2);
    const float4 dq4 = *(const float4*)(dq2 + rbase);
    const float* dqp = (const float*)&dq4;
#pragma unroll
    for (int j = 0; j < 4; ++j) {
      const int col = nBase + wn * 64 + j * 16 + fr;
#pragma unroll
      for (int r = 0; r < 4; ++r) {
        const size_t idx = (size_t)(rbase + r) * H_DIM + col;
        out[idx] = (float)acc[i][j][r] * dqp[r] * dqw + x[idx];
      }
    }
  }
}

extern "C" void kernel_launch(void* const* d_in, const int* in_sizes, int n_in,
                              void* d_out, int out_size, void* d_ws, size_t ws_size,
                              hipStream_t stream) {
  const float* x  = (const float*)d_in[0];
  const float* nw = (const float*)d_in[1];
  const float* wu = (const float*)d_in[2];
  const float* wd = (const float*)d_in[3];
  float* out = (float*)d_out;
  char* ws = (char*)d_ws;
  if (ws_size < WS_NEEDED) return;  // workspace too small: leave output poisoned (diagnostic)

  __half* h2     = (__half*)(ws + OFF_H2);
  float* rs2     = (float*)(ws + OFF_RS2);
  char* xq       = ws + OFF_XQ;
  char* wqu      = ws + OFF_WQU;
  char* wqd      = ws + OFF_WQD;
  float* dqx     = (float*)(ws + OFF_DQX);
  float* dq2     = (float*)(ws + OFF_DQ2);
  float* pmax    = (float*)(ws + OFF_PMAX);
  float* wpart   = (float*)(ws + OFF_WPART);
  float* wsc     = (float*)(ws + OFF_WSC);

  k_wabs<<<2048, 256, 0, stream>>>(wu, wd, wpart);
  k_wscale<<<2, 256, 0, stream>>>(wpart, wsc);
  k_wquant<<<8192, 256, 0, stream>>>(wu, wd, wqu, wqd, wsc);
  k_rmsnorm_quant<<<M_TOK, 256, 0, stream>>>(x, nw, xq, dqx);
  k_gemm1<<<dim3(M_TOK / 256, F_DIM / 256), 512, 0, stream>>>(xq, wqu, wsc, dqx, h2, pmax);
  k_rowscale<<<M_TOK / 256, 256, 0, stream>>>(pmax, dq2, rs2);
  k_gemm2<<<dim3(M_TOK / 256, H_DIM / 256), 512, 0, stream>>>(h2, wqd, wsc, dq2, rs2, x, out);
}